// Round 1
// 1215.599 us; speedup vs baseline: 2.5275x; 2.5275x over previous
//
#include <hip/hip_runtime.h>
#include <cmath>

// ---- problem constants ----
#define NBS 8
#define NC 20
#define NFH 480
#define NFW 640
#define NHS 240
#define NWS 320
#define NM 480
#define NPIX (NM * NM)   // 230400
#define NVR 100
#define NPIXELS (NBS * NHS * NWS)  // 614400
#define PPB (NHS * NWS)            // 76800 pixels per batch

// ---- d_out layout (float element offsets) ----
// out = [translated (8,20,480,480) | map_pred | map_pred_stair | poses (8,3)]
constexpr long long T_OFF    = 0LL;
constexpr long long P_OFF    = 36864000LL;   // 8*20*230400
constexpr long long S_OFF    = 73728000LL;
constexpr long long POSE_OFF = 110592000LL;

// scratch lives in the P region (dead until k_pred, which runs last)
constexpr long long SMAP_OFF = P_OFF;                     // 8*19*10000 floats
constexpr long long PAR_OFF  = SMAP_OFF + 1520000LL;      // 64 floats
constexpr long long TS_OFF   = PAR_OFF + 64LL;            // 8*230400 (tstair ch0)
constexpr long long POOL_OFF = TS_OFF + 1843200LL;        // 614400*16 pooled sem
constexpr long long REC_OFF  = POOL_OFF + 9830400LL;      // 614400 float4 records
constexpr long long ENT_OFF  = REC_OFF + 9830400LL;       // 614400 float4 entries
constexpr long long CNT_OFF  = ENT_OFF + 9830400LL;       // 80000 u32 counts
constexpr long long OFF2_OFF = CNT_OFF + 80000LL;         // 80000 u32 offsets
constexpr long long CUR_OFF  = OFF2_OFF + 80000LL;        // 80000 u32 cursors
// end = P_OFF + 33,094,464 < P_OFF + 36,864,000  OK

__device__ __forceinline__ float clamp01(float x) {
    return fminf(fmaxf(x, 0.0f), 1.0f);
}

// ---------------- K1: poses + affine params ----------------
__global__ void k_pose(const float* __restrict__ pose_obs,
                       const float* __restrict__ poses_last,
                       float* __restrict__ outp) {
    int b = threadIdx.x;
    if (b >= NBS) return;
    float* pose_out = outp + POSE_OFF;
    float* par = outp + PAR_OFF;
    const float DEGf = 57.29577951308232f;
    float tr = poses_last[b * 3 + 2] / DEGf;
    float s_tr = sinf(tr), c_tr = cosf(tr);
    float ny = poses_last[b * 3 + 1] + pose_obs[b * 3 + 0] * s_tr + pose_obs[b * 3 + 1] * c_tr;
    float nx = poses_last[b * 3 + 0] + pose_obs[b * 3 + 0] * c_tr - pose_obs[b * 3 + 1] * s_tr;
    float no = poses_last[b * 3 + 2] + pose_obs[b * 3 + 2] * DEGf;
    no = fmodf(no - 180.0f, 360.0f) + 180.0f;
    no = fmodf(no + 180.0f, 360.0f) - 180.0f;
    pose_out[b * 3 + 0] = nx;
    pose_out[b * 3 + 1] = ny;
    pose_out[b * 3 + 2] = no;
    float stx = -((nx * 100.0f) / 5.0f - 240.0f) / 240.0f;
    float sty = -((ny * 100.0f) / 5.0f - 240.0f) / 240.0f;
    float stt = ((90.0f - no) * 3.14159265358979323846f) / 180.0f;
    par[b * 4 + 0] = cosf(stt);
    par[b * 4 + 1] = sinf(stt);
    par[b * 4 + 2] = stx;
    par[b * 4 + 3] = sty;
    if (b == 0) {
        int sy = (int)((ny * 100.0f) / 5.0f);   // truncation matches astype(int32)
        int sx = (int)((nx * 100.0f) / 5.0f);
        sy = min(max(sy, 30), NM - 31);
        sx = min(max(sx, 30), NM - 31);
        par[32] = (float)sy;
        par[33] = (float)sx;
    }
}

// ---------------- K2a: project pixels, count per bucket, pool sem ----------------
// Record per pixel: {posx, posy, posz, alive}. Bucket = (b, floor(posx), floor(posy)).
__global__ void k_count(const float* __restrict__ obs,
                        const float* __restrict__ eve, float camf,
                        unsigned int* __restrict__ counts,
                        float* __restrict__ pooled,
                        float4* __restrict__ rec) {
    int tid = blockIdx.x * blockDim.x + threadIdx.x;
    if (tid >= NPIXELS) return;
    int b = tid / PPB;
    int p = tid % PPB;
    int iy = p / NWS, ix = p % NWS;
    const float* ob = obs + (long long)b * NC * NFH * NFW;
    float depth = ob[(3LL * NFH + 2 * iy) * NFW + 2 * ix];
    float th = eve[b] * 0.017453292519943295f;
    float ct = cosf(th), st = sinf(th);
    float X = ((float)(2 * ix) - 319.5f) * depth / camf;
    float Z = ((float)(479 - 2 * iy) - 239.5f) * depth / camf;
    float Yr = ct * depth - st * Z;
    float Zr = st * depth + ct * Z + 88.0f;
    float Xs = X + 250.0f;
    float cx = ((Xs / 5.0f) - 50.0f) / 100.0f * 2.0f;
    float cy = ((Yr / 5.0f) - 50.0f) / 100.0f * 2.0f;
    float cz = ((Zr / 5.0f) - 16.0f) / 48.0f * 2.0f;
    float posx = (cx * 100.0f) / 2.0f + 50.0f;
    float posy = (cy * 100.0f) / 2.0f + 50.0f;
    float posz = (cz * 48.0f) / 2.0f + 24.0f;
    bool alive = (posx > 0.0f) && (posx < 100.0f) &&
                 (posy > 0.0f) && (posy < 100.0f) &&
                 (posz > 0.0f) && (posz < 48.0f);
    rec[tid] = make_float4(posx, posy, posz, alive ? 1.0f : 0.0f);
    if (!alive) return;
    int fx = (int)floorf(posx);   // in [0,99]
    int fy = (int)floorf(posy);
    atomicAdd(&counts[b * 10000 + fx * 100 + fy], 1u);
    // pooled 2x2-mean sem, only if some z-corner can land in [13,35)
    if (posz > 12.0f && posz < 35.0f) {
        float sem[16];
#pragma unroll
        for (int k = 0; k < 16; ++k) {
            const float* q = ob + ((long long)(4 + k) * NFH + 2 * iy) * NFW + 2 * ix;
            sem[k] = (q[0] + q[1] + q[NFW] + q[NFW + 1]) * 0.25f;
        }
        float4* pp = (float4*)(pooled + (long long)tid * 16);
#pragma unroll
        for (int g = 0; g < 4; ++g)
            pp[g] = make_float4(sem[4 * g], sem[4 * g + 1], sem[4 * g + 2], sem[4 * g + 3]);
    }
}

// ---------------- K2b: per-batch exclusive prefix sum over 10000 buckets ----------------
__global__ void k_scan(const unsigned int* __restrict__ counts,
                       unsigned int* __restrict__ offs,
                       unsigned int* __restrict__ curs) {
    int b = blockIdx.x;          // 8 blocks
    int lane = threadIdx.x;      // 64
    unsigned int base = 0;
    for (int c0 = 0; c0 < 10000; c0 += 64) {
        int i = c0 + lane;
        unsigned int v = (i < 10000) ? counts[b * 10000 + i] : 0u;
        unsigned int s = v;
#pragma unroll
        for (int d = 1; d < 64; d <<= 1) {
            unsigned int t = __shfl_up(s, d);
            if (lane >= d) s += t;
        }
        if (i < 10000) {
            unsigned int excl = base + s - v;
            offs[b * 10000 + i] = excl;
            curs[b * 10000 + i] = excl;
        }
        base += __shfl(s, 63);
    }
}

// ---------------- K2c: fill bucket entries ----------------
__global__ void k_fill(const float4* __restrict__ rec,
                       unsigned int* __restrict__ curs,
                       float4* __restrict__ entries) {
    int tid = blockIdx.x * blockDim.x + threadIdx.x;
    if (tid >= NPIXELS) return;
    float4 r = rec[tid];
    if (r.w == 0.0f) return;
    int b = tid / PPB;
    int fx = (int)floorf(r.x);
    int fy = (int)floorf(r.y);
    unsigned int slot = atomicAdd(&curs[b * 10000 + fx * 100 + fy], 1u);
    entries[(long long)b * PPB + slot] =
        make_float4(r.x, r.y, r.z, __uint_as_float((unsigned int)tid));
}

// ---------------- K2d: per-column gather-accumulate in LDS + fused projection ----------------
// One 64-lane wave per voxel column (b, x, y). Reads the 4 neighboring floor-cell
// buckets; accumulates 48 occ + 22*16 sem in LDS; rounds; writes 19 smap channels.
// smap channels: 0=fp_map, 1=fp_exp, 2=fp_stair, 3..18 = cat0..15 ; ij = y*100 + x
__global__ void __launch_bounds__(64) k_accum(const float4* __restrict__ entries,
                                              const unsigned int* __restrict__ counts,
                                              const unsigned int* __restrict__ offs,
                                              const float* __restrict__ pooled,
                                              float* __restrict__ smap) {
    int col = blockIdx.x;            // 0..79999
    int b = col / 10000;
    int xy = col % 10000;
    int x = xy / 100, y = xy % 100;
    __shared__ float acc[400];       // [0..48) occ(z), [48 + (z-13)*16 + k] sem
    int lane = threadIdx.x;
    for (int i = lane; i < 400; i += 64) acc[i] = 0.0f;
    __syncthreads();
    if (x >= 1 && y >= 1) {          // columns at x==0 or y==0 never get weight (safe mask)
        const float4* eb = entries + (long long)b * PPB;
#pragma unroll
        for (int dbx = 0; dbx < 2; ++dbx) {
            int bx = x - 1 + dbx;
            if (bx > 99) continue;   // bx >= 0 guaranteed (x>=1)
#pragma unroll
            for (int dby = 0; dby < 2; ++dby) {
                int by = y - 1 + dby;
                if (by > 99) continue;
                int bucket = b * 10000 + bx * 100 + by;
                unsigned int n = counts[bucket];
                unsigned int s0 = offs[bucket];
                for (unsigned int e0 = 0; e0 < n; e0 += 64) {
                    unsigned int e = e0 + (unsigned int)lane;
                    if (e < n) {
                        float4 ent = eb[s0 + e];
                        float wx = 1.0f - fabsf(ent.x - (float)x);
                        float wy = 1.0f - fabsf(ent.y - (float)y);
                        float wxy = wx * wy;
                        if (wxy > 0.0f) {
                            float posz = ent.z;
                            float fz = floorf(posz);
#pragma unroll
                            for (int d = 0; d < 2; ++d) {
                                float zf = fz + (float)d;
                                int z = (int)zf;
                                if (z < 1 || z > 47) continue;
                                float w = wxy * (1.0f - fabsf(posz - zf));
                                if (w <= 0.0f) continue;
                                atomicAdd(&acc[z], w);
                                if (z >= 13 && z < 35) {
                                    const float* sp =
                                        pooled + (long long)__float_as_uint(ent.w) * 16;
                                    float* ap = &acc[48 + (z - 13) * 16];
#pragma unroll
                                    for (int k = 0; k < 16; ++k)
                                        atomicAdd(&ap[k], sp[k] * w);
                                }
                            }
                        }
                    }
                }
            }
        }
    }
    __syncthreads();
    for (int i = lane; i < 400; i += 64) acc[i] = rintf(acc[i]);
    __syncthreads();
    float* sm = smap + (long long)b * 19 * 10000;
    int ij = y * 100 + x;
    if (lane < 16) {
        float s = 0.0f;
#pragma unroll
        for (int z = 13; z < 35; ++z) s += acc[48 + (z - 13) * 16 + lane];
        sm[(3 + lane) * 10000 + ij] = clamp01(s / 5.0f);   // CAT_T = 5
    } else if (lane == 16) {
        float s = 0.0f;
        for (int z = 13; z < 35; ++z) s += acc[z];
        sm[ij] = clamp01(s);                               // fp_map (MAP_T = 1)
    } else if (lane == 17) {
        float s = 0.0f;
        for (int z = 0; z < 48; ++z) s += acc[z];
        sm[10000 + ij] = clamp01(s);                       // fp_exp (EXP_T = 1)
    } else if (lane == 18) {
        float s = 0.0f;
        for (int z = 20; z < 25; ++z) s += acc[z];
        sm[20000 + ij] = clamp01(s);                       // fp_stair
    }
}

// ---------------- K4: fused rotate+translate grid_sample ----------------
__global__ void k_translate(float* __restrict__ outp,
                            const float* __restrict__ smap,
                            const float* __restrict__ par,
                            float* __restrict__ tstair) {
    int tid = blockIdx.x * blockDim.x + threadIdx.x;
    if (tid >= NBS * NPIX) return;
    int b = tid / NPIX;
    int ij = tid % NPIX;
    int i = ij / NM, j = ij % NM;
    float c = par[b * 4 + 0], s = par[b * 4 + 1];
    float stx = par[b * 4 + 2], sty = par[b * 4 + 3];
    float gx = (((float)j + 0.5f) * 2.0f) / 480.0f - 1.0f;
    float gy = (((float)i + 0.5f) * 2.0f) / 480.0f - 1.0f;
    float px = ((gx + stx) + 1.0f) * 479.0f / 2.0f;
    float py = ((gy + sty) + 1.0f) * 479.0f / 2.0f;
    float x0 = floorf(px), y0 = floorf(py);
    float wx1 = px - x0, wx0 = 1.0f - wx1;
    float wy1 = py - y0, wy0 = 1.0f - wy1;
    int offs[16];
    float wts[16];
    int nt = 0;
#pragma unroll
    for (int t = 0; t < 4; ++t) {  // outer taps in reference gather order
        int ox = t & 1, oy = t >> 1;
        float xo = x0 + (float)ox, yo = y0 + (float)oy;
        if (!(xo >= 0.0f && xo < 480.0f && yo >= 0.0f && yo < 480.0f)) continue;
        float wo = (ox ? wx1 : wx0) * (oy ? wy1 : wy0);
        int ixo = (int)xo, iyo = (int)yo;
        float gx2 = (((float)ixo + 0.5f) * 2.0f) / 480.0f - 1.0f;
        float gy2 = (((float)iyo + 0.5f) * 2.0f) / 480.0f - 1.0f;
        float rx = c * gx2 - s * gy2;
        float ry = s * gx2 + c * gy2;
        float qx = (rx + 1.0f) * 479.0f / 2.0f;
        float qy = (ry + 1.0f) * 479.0f / 2.0f;
        float xq0 = floorf(qx), yq0 = floorf(qy);
        float u1 = qx - xq0, u0 = 1.0f - u1;
        float v1 = qy - yq0, v0 = 1.0f - v1;
#pragma unroll
        for (int t2 = 0; t2 < 4; ++t2) {
            int ax = t2 & 1, ay = t2 >> 1;
            float xa = xq0 + (float)ax, ya = yq0 + (float)ay;
            // agent_view nonzero window: rows [240,340), cols [190,290)
            if (xa >= 190.0f && xa < 290.0f && ya >= 240.0f && ya < 340.0f) {
                float w = wo * ((ax ? u1 : u0) * (ay ? v1 : v0));
                if (w != 0.0f) {
                    offs[nt] = ((int)ya - 240) * 100 + ((int)xa - 190);
                    wts[nt] = w;
                    ++nt;
                }
            }
        }
    }
    float* To = outp + T_OFF;
    long long obase = (long long)b * NC * NPIX + ij;
    if (nt == 0) {  // fast path: entirely outside agent-view support
#pragma unroll
        for (int ch = 0; ch < NC; ++ch) To[obase + (long long)ch * NPIX] = 0.0f;
        tstair[(long long)b * NPIX + ij] = 0.0f;
        return;
    }
    const float* sm = smap + (long long)b * 19 * 10000;
    float a0 = 0.0f, a1 = 0.0f, as_ = 0.0f;
    float cat[16];
#pragma unroll
    for (int k = 0; k < 16; ++k) cat[k] = 0.0f;
    for (int t = 0; t < nt; ++t) {
        float w = wts[t];
        int o = offs[t];
        a0 += w * sm[o];
        a1 += w * sm[10000 + o];
        as_ += w * sm[20000 + o];
#pragma unroll
        for (int k = 0; k < 16; ++k) cat[k] += w * sm[(3 + k) * 10000 + o];
    }
    To[obase] = a0;
    To[obase + (long long)NPIX] = a1;
    To[obase + 2LL * NPIX] = 0.0f;
    To[obase + 3LL * NPIX] = 0.0f;
#pragma unroll
    for (int k = 0; k < 16; ++k) To[obase + (long long)(4 + k) * NPIX] = cat[k];
    tstair[(long long)b * NPIX + ij] = as_;
}

// ---------------- K5: map_pred_stair (writes full S region) ----------------
__global__ void k_stair(const float* __restrict__ T, const float* __restrict__ tstair,
                        const float* __restrict__ par, const float* __restrict__ maps_last,
                        const float* __restrict__ eve, float* __restrict__ outS) {
    int tid = blockIdx.x * blockDim.x + threadIdx.x;
    if (tid >= NBS * NPIX) return;
    int b = tid / NPIX;
    int ij = tid % NPIX;
    int i = ij / NM, j = ij % NM;
    bool eve0 = (eve[b] == 0.0f);
    const float* Tb = T + (long long)b * NC * NPIX;
    float ts0 = tstair[(long long)b * NPIX + ij];
    float t1 = Tb[(long long)NPIX + ij];
    if (b == 0) {
        float dy = (float)i - par[32] + 0.5f;
        float dx = (float)j - par[33] + 0.5f;
        float mask = (dy * dy + dx * dx <= 900.0f) ? 1.0f : 0.0f;
        ts0 *= mask;
        t1 *= mask;
    }
    bool flag = (t1 - ts0) > 0.8f;
    const float* ml = maps_last + (long long)b * NC * NPIX;
    long long obase = (long long)b * NC * NPIX + ij;
#pragma unroll
    for (int ch = 0; ch < NC; ++ch) {
        float tch = (ch == 0) ? ts0 : (ch == 1) ? t1 : Tb[(long long)ch * NPIX + ij];
        float m3 = fmaxf(ml[(long long)ch * NPIX + ij], tch);
        outS[obase + (long long)ch * NPIX] = (ch == 0 && eve0 && flag) ? 0.0f : m3;
    }
}

// ---------------- K6: map_pred (writes full P region) ----------------
__global__ void k_pred(const float* __restrict__ T, const float* __restrict__ maps_last,
                       const float* __restrict__ eve, float* __restrict__ outP) {
    int tid = blockIdx.x * blockDim.x + threadIdx.x;
    if (tid >= NBS * NPIX) return;
    int b = tid / NPIX;
    int ij = tid % NPIX;
    int i = ij / NM, j = ij % NM;
    const float* Tb = T + (long long)b * NC * NPIX;
    float mp = -INFINITY;  // maxpool3 with -inf padding == max over in-bounds nbrs
#pragma unroll
    for (int di = -1; di <= 1; ++di) {
        int ii = i + di;
        if (ii < 0 || ii >= NM) continue;
#pragma unroll
        for (int dj = -1; dj <= 1; ++dj) {
            int jj = j + dj;
            if (jj < 0 || jj >= NM) continue;
            mp = fmaxf(mp, Tb[(long long)ii * NM + jj]);
        }
    }
    float t1 = Tb[(long long)NPIX + ij];
    bool flag = (t1 - mp) > 0.8f;
    bool eve0 = (eve[b] == 0.0f);
    const float* ml = maps_last + (long long)b * NC * NPIX;
    long long obase = (long long)b * NC * NPIX + ij;
#pragma unroll
    for (int ch = 0; ch < NC; ++ch) {
        float m2 = fmaxf(ml[(long long)ch * NPIX + ij], Tb[(long long)ch * NPIX + ij]);
        outP[obase + (long long)ch * NPIX] = (ch == 0 && eve0 && flag) ? 0.0f : m2;
    }
}

extern "C" void kernel_launch(void* const* d_in, const int* in_sizes, int n_in,
                              void* d_out, int out_size, void* d_ws, size_t ws_size,
                              hipStream_t stream) {
    const float* obs = (const float*)d_in[0];
    const float* pose_obs = (const float*)d_in[1];
    const float* maps_last = (const float*)d_in[2];
    const float* poses_last = (const float*)d_in[3];
    const float* eve = (const float*)d_in[4];
    float* outp = (float*)d_out;

    // host-side exact camera focal constant (matches np.float64 -> f32)
    float camf = (float)(320.0 / tan(39.5 * M_PI / 180.0));

    unsigned int* counts = (unsigned int*)(outp + CNT_OFF);
    unsigned int* offs2  = (unsigned int*)(outp + OFF2_OFF);
    unsigned int* curs   = (unsigned int*)(outp + CUR_OFF);
    float*  pooled  = outp + POOL_OFF;
    float4* rec     = (float4*)(outp + REC_OFF);
    float4* entries = (float4*)(outp + ENT_OFF);

    // zero only the 320 KB bucket counters (128 MB voxel memset is gone)
    hipMemsetAsync(counts, 0, 80000 * sizeof(unsigned int), stream);

    k_pose<<<1, 64, 0, stream>>>(pose_obs, poses_last, outp);

    k_count<<<NPIXELS / 256, 256, 0, stream>>>(obs, eve, camf, counts, pooled, rec);

    k_scan<<<NBS, 64, 0, stream>>>(counts, offs2, curs);

    k_fill<<<NPIXELS / 256, 256, 0, stream>>>(rec, curs, entries);

    k_accum<<<NBS * 10000, 64, 0, stream>>>(entries, counts, offs2, pooled,
                                            outp + SMAP_OFF);

    k_translate<<<(NBS * NPIX) / 256, 256, 0, stream>>>(outp, outp + SMAP_OFF,
                                                        outp + PAR_OFF, outp + TS_OFF);

    k_stair<<<(NBS * NPIX) / 256, 256, 0, stream>>>(outp + T_OFF, outp + TS_OFF,
                                                    outp + PAR_OFF, maps_last, eve,
                                                    outp + S_OFF);

    k_pred<<<(NBS * NPIX) / 256, 256, 0, stream>>>(outp + T_OFF, maps_last, eve,
                                                   outp + P_OFF);
}